// Round 2
// baseline (637.128 us; speedup 1.0000x reference)
//
#include <hip/hip_runtime.h>
#include <hip/hip_bf16.h>

#define B_TOT 131072
#define D     32
#define H1    50
#define QF    528     // tril feature count
#define H2    700
#define KP    544     // quad K padded to 17*32
#define NPH   768     // H2 padded to 8 waves * 96
#define W2B_STRIDE 800  // W2bT k-stride (>= 720+64, 16B-aligned)

typedef __attribute__((ext_vector_type(8))) short  short8x;
typedef __attribute__((ext_vector_type(4))) float  floatx4;

static __device__ __forceinline__ unsigned short f2bf(float f) {
    __hip_bfloat16 h = __float2bfloat16(f);   // RNE
    return __builtin_bit_cast(unsigned short, h);
}

static __device__ __forceinline__ float tanh_fast(float x) {
    float xc = fminf(15.f, fmaxf(-15.f, x));
    float e  = __expf(2.f * xc);
    return 1.f - 2.f * __builtin_amdgcn_rcpf(e + 1.f);
}

// ---------------- prep: convert/pad weights into workspace ----------------
// W2aT[NPH][KP] bf16 : W2aT[c][k] = W2a[k][c] (zeros for c>=700 or k>=528)
// W2bT[32][W2B_STRIDE] bf16 : W2bT[c][k] = W2b[k][c] (zeros k>=700)
// b2ap[NPH] f32 : padded b2a
__global__ void prep_kernel(const float* __restrict__ W2a, const float* __restrict__ b2a,
                            const float* __restrict__ W2b,
                            unsigned short* __restrict__ W2aT,
                            unsigned short* __restrict__ W2bT,
                            float* __restrict__ b2ap) {
    int idx = blockIdx.x * 256 + threadIdx.x;
    const int N1 = NPH * KP;            // 417792
    const int N2 = 32 * W2B_STRIDE;     // 25600
    if (idx < N1) {
        int c = idx / KP, k = idx - c * KP;
        float v = (c < H2 && k < QF) ? W2a[k * H2 + c] : 0.f;
        W2aT[idx] = f2bf(v);
    } else if (idx < N1 + N2) {
        int j = idx - N1;
        int c = j / W2B_STRIDE, k = j - c * W2B_STRIDE;
        float v = (k < H2) ? W2b[k * D + c] : 0.f;
        W2bT[j] = f2bf(v);
    } else if (idx < N1 + N2 + NPH) {
        int k = idx - N1 - N2;
        b2ap[k] = (k < H2) ? b2a[k] : 0.f;
    }
}

// ---------------- fused main kernel ----------------
// __launch_bounds__(512, 1): LDS (118 KB) already limits to 1 block/CU, so
// capping VGPRs at 128 (the old min_waves=2 setting) bought nothing and
// caused massive scratch spills (600 MB HBM write traffic/dispatch).
__global__ __launch_bounds__(512, 1) void fused_kernel(
    const float* __restrict__ y,   const float* __restrict__ W1a,
    const float* __restrict__ b1a, const float* __restrict__ W1b,
    const float* __restrict__ b1b, const float* __restrict__ b2b,
    const unsigned short* __restrict__ W2aT, const unsigned short* __restrict__ W2bT,
    const float* __restrict__ b2ap, float* __restrict__ out) {

    __shared__ float          yls[64][36];     // y tile (stride 36: float4-aligned)
    __shared__ unsigned short quadls[64][552]; // bf16 quad, K padded to 544 (+8 bank pad)
    __shared__ float          h1ls[64][51];    // net1 hidden
    __shared__ float          outls[64][36];   // output accumulator
    __shared__ unsigned short hst[8][16][72];  // per-wave h re-stage tile

    const int tid  = threadIdx.x;
    const int lane = tid & 63;
    const int w    = tid >> 6;      // wave 0..7
    const int l15  = lane & 15;
    const int lg   = lane >> 4;     // 0..3
    const int row0 = blockIdx.x * 64;

    // ---- Phase A: load y tile, zero hst pad cols ----
    {
        int e = tid * 4;                 // 2048 floats total
        int r = e >> 5, c = e & 31;
        floatx4 v = *reinterpret_cast<const floatx4*>(y + (row0 + r) * D + c);
        *reinterpret_cast<floatx4*>(&yls[r][c]) = v;
    }
    for (int e = tid; e < 8 * 16 * 24; e += 512) {
        int ww = e / 384, rr = (e / 24) & 15, cc = 48 + (e % 24);
        hst[ww][rr][cc] = 0;
    }
    __syncthreads();

    // ---- Phase B: build quad (bf16) + net1 hidden ----
    #pragma unroll
    for (int s = 0; s < 4; ++s) {
        int task = tid + s * 512;        // (row, i) : 64*32 tasks
        int r = task >> 5, i = task & 31;
        int base = (i * (i + 1)) >> 1;
        float yi = yls[r][i];
        for (int j4 = 0; j4 <= i; j4 += 4) {
            floatx4 yv = *reinterpret_cast<const floatx4*>(&yls[r][j4]);
            #pragma unroll
            for (int jj = 0; jj < 4; ++jj) {
                int j = j4 + jj;
                if (j <= i) quadls[r][base + j] = f2bf(yi * yv[jj]);
            }
        }
    }
    for (int e = tid; e < 64 * 16; e += 512)   // zero K-pad 528..543
        quadls[e >> 4][528 + (e & 15)] = 0;

    if (tid < 208) {                     // net1 hidden: 16 row-groups x 13 col-groups
        int rowg = tid / 13, jg = tid - rowg * 13;
        int r0 = rowg * 4, c0 = jg * 4;
        int lim = (c0 + 4 <= H1) ? 4 : (H1 - c0);
        float acc[4][4];
        #pragma unroll
        for (int rr = 0; rr < 4; ++rr)
            #pragma unroll
            for (int jj = 0; jj < 4; ++jj)
                acc[rr][jj] = (jj < lim) ? b1a[c0 + jj] : 0.f;
        for (int i = 0; i < D; ++i) {
            float wv[4];
            #pragma unroll
            for (int jj = 0; jj < 4; ++jj)
                wv[jj] = (jj < lim) ? W1a[i * H1 + c0 + jj] : 0.f;
            #pragma unroll
            for (int rr = 0; rr < 4; ++rr) {
                float yv = yls[r0 + rr][i];
                #pragma unroll
                for (int jj = 0; jj < 4; ++jj) acc[rr][jj] += yv * wv[jj];
            }
        }
        #pragma unroll
        for (int rr = 0; rr < 4; ++rr)
            #pragma unroll
            for (int jj = 0; jj < 4; ++jj)
                if (jj < lim) h1ls[r0 + rr][c0 + jj] = tanh_fast(acc[rr][jj]);
    }
    __syncthreads();

    // ---- Phase C: out1 + all output biases into outls ----
    {
        int r = tid >> 3, c0 = (tid & 7) * 4;
        floatx4 acc;
        #pragma unroll
        for (int jj = 0; jj < 4; ++jj) acc[jj] = b1b[c0 + jj] + b2b[c0 + jj];
        for (int k = 0; k < H1; ++k) {
            float hv = h1ls[r][k];
            floatx4 wv = *reinterpret_cast<const floatx4*>(W1b + k * D + c0);
            #pragma unroll
            for (int jj = 0; jj < 4; ++jj) acc[jj] += hv * wv[jj];
        }
        *reinterpret_cast<floatx4*>(&outls[r][c0]) = acc;
    }
    __syncthreads();

    // ---- Main: wave w owns hidden cols [w*96, w*96+96), two halves of 48 ----
    floatx4 o2[4][2];
    #pragma unroll
    for (int m = 0; m < 4; ++m)
        #pragma unroll
        for (int of = 0; of < 2; ++of) o2[m][of] = (floatx4){0.f, 0.f, 0.f, 0.f};

    for (int half = 0; half < 2; ++half) {
        const int hb = w * 96 + half * 48;
        floatx4 hacc[4][3];
        #pragma unroll
        for (int m = 0; m < 4; ++m)
            #pragma unroll
            for (int nf = 0; nf < 3; ++nf) hacc[m][nf] = (floatx4){0.f, 0.f, 0.f, 0.f};

        const unsigned short* bpt = W2aT + (hb + l15) * KP + lg * 8;

        short8x b[3];
        #pragma unroll
        for (int nf = 0; nf < 3; ++nf)
            b[nf] = *reinterpret_cast<const short8x*>(bpt + nf * 16 * KP);

        #pragma unroll
        for (int k = 0; k < 17; ++k) {
            short8x a[4];
            #pragma unroll
            for (int m = 0; m < 4; ++m)
                a[m] = *reinterpret_cast<const short8x*>(&quadls[m * 16 + l15][k * 32 + lg * 8]);
            short8x bn[3];
            if (k < 16) {
                #pragma unroll
                for (int nf = 0; nf < 3; ++nf)
                    bn[nf] = *reinterpret_cast<const short8x*>(bpt + nf * 16 * KP + (k + 1) * 32);
            }
            #pragma unroll
            for (int m = 0; m < 4; ++m)
                #pragma unroll
                for (int nf = 0; nf < 3; ++nf)
                    hacc[m][nf] = __builtin_amdgcn_mfma_f32_16x16x32_bf16(a[m], b[nf], hacc[m][nf], 0, 0, 0);
            #pragma unroll
            for (int nf = 0; nf < 3; ++nf) b[nf] = bn[nf];
        }

        // epilogue: bias + tanh -> bf16 re-stage -> second GEMM (K=64 incl zero pad)
        float bias[3];
        #pragma unroll
        for (int nf = 0; nf < 3; ++nf) bias[nf] = b2ap[hb + nf * 16 + l15];

        short8x bw[2][2];
        #pragma unroll
        for (int ks = 0; ks < 2; ++ks)
            #pragma unroll
            for (int of = 0; of < 2; ++of)
                bw[ks][of] = *reinterpret_cast<const short8x*>(
                    W2bT + (of * 16 + l15) * W2B_STRIDE + hb + ks * 32 + lg * 8);

        #pragma unroll
        for (int m = 0; m < 4; ++m) {
            #pragma unroll
            for (int nf = 0; nf < 3; ++nf)
                #pragma unroll
                for (int r = 0; r < 4; ++r)
                    hst[w][lg * 4 + r][nf * 16 + l15] =
                        f2bf(tanh_fast(hacc[m][nf][r] + bias[nf]));
            short8x aa0 = *reinterpret_cast<const short8x*>(&hst[w][l15][lg * 8]);
            short8x aa1 = *reinterpret_cast<const short8x*>(&hst[w][l15][32 + lg * 8]);
            o2[m][0] = __builtin_amdgcn_mfma_f32_16x16x32_bf16(aa0, bw[0][0], o2[m][0], 0, 0, 0);
            o2[m][1] = __builtin_amdgcn_mfma_f32_16x16x32_bf16(aa0, bw[0][1], o2[m][1], 0, 0, 0);
            o2[m][0] = __builtin_amdgcn_mfma_f32_16x16x32_bf16(aa1, bw[1][0], o2[m][0], 0, 0, 0);
            o2[m][1] = __builtin_amdgcn_mfma_f32_16x16x32_bf16(aa1, bw[1][1], o2[m][1], 0, 0, 0);
        }
    }

    // ---- deterministic cross-wave reduction into outls ----
    for (int ww = 0; ww < 8; ++ww) {
        if (w == ww) {
            #pragma unroll
            for (int m = 0; m < 4; ++m)
                #pragma unroll
                for (int of = 0; of < 2; ++of)
                    #pragma unroll
                    for (int r = 0; r < 4; ++r)
                        outls[m * 16 + lg * 4 + r][of * 16 + l15] += o2[m][of][r];
        }
        __syncthreads();
    }

    // ---- write out ----
    {
        int e = tid * 4;
        int r = e >> 5, c = e & 31;
        floatx4 v = *reinterpret_cast<const floatx4*>(&outls[r][c]);
        *reinterpret_cast<floatx4*>(out + (row0 + r) * D + c) = v;
    }
}

extern "C" void kernel_launch(void* const* d_in, const int* in_sizes, int n_in,
                              void* d_out, int out_size, void* d_ws, size_t ws_size,
                              hipStream_t stream) {
    const float* y   = (const float*)d_in[1];
    const float* W1a = (const float*)d_in[2];
    const float* b1a = (const float*)d_in[3];
    const float* W1b = (const float*)d_in[4];
    const float* b1b = (const float*)d_in[5];
    const float* W2a = (const float*)d_in[6];
    const float* b2a = (const float*)d_in[7];
    const float* W2b = (const float*)d_in[8];
    const float* b2b = (const float*)d_in[9];

    unsigned short* W2aT = (unsigned short*)d_ws;                          // 835584 B
    unsigned short* W2bT = (unsigned short*)((char*)d_ws + 835584);        //  51200 B
    float*          b2ap = (float*)((char*)d_ws + 835584 + 51200);         //   3072 B

    const int prep_tasks = NPH * KP + 32 * W2B_STRIDE + NPH;               // 444160
    prep_kernel<<<(prep_tasks + 255) / 256, 256, 0, stream>>>(W2a, b2a, W2b, W2aT, W2bT, b2ap);
    fused_kernel<<<B_TOT / 64, 512, 0, stream>>>(y, W1a, b1a, W1b, b1b, b2b,
                                                 W2aT, W2bT, b2ap, (float*)d_out);
}

// Round 3
// 629.690 us; speedup vs baseline: 1.0118x; 1.0118x over previous
//
#include <hip/hip_runtime.h>
#include <hip/hip_bf16.h>

#define B_TOT 131072
#define D     32
#define H1    50
#define QF    528     // tril feature count
#define H2    700
#define KP    544     // quad K padded to 17*32
#define NPH   768     // H2 padded to 8 waves * 96
#define W2B_STRIDE 800  // W2bT k-stride (>= 720+64, 16B-aligned)

typedef __attribute__((ext_vector_type(8))) short  short8x;
typedef __attribute__((ext_vector_type(4))) float  floatx4;

static __device__ __forceinline__ unsigned short f2bf(float f) {
    __hip_bfloat16 h = __float2bfloat16(f);   // RNE
    return __builtin_bit_cast(unsigned short, h);
}

static __device__ __forceinline__ float tanh_fast(float x) {
    float xc = fminf(15.f, fmaxf(-15.f, x));
    float e  = __expf(2.f * xc);
    return 1.f - 2.f * __builtin_amdgcn_rcpf(e + 1.f);
}

// ---------------- prep: convert/pad weights into workspace ----------------
// W2aT[NPH][KP] bf16 : W2aT[c][k] = W2a[k][c] (zeros for c>=700 or k>=528)
// W2bT[32][W2B_STRIDE] bf16 : W2bT[c][k] = W2b[k][c] (zeros k>=700)
// b2ap[NPH] f32 : padded b2a
__global__ void prep_kernel(const float* __restrict__ W2a, const float* __restrict__ b2a,
                            const float* __restrict__ W2b,
                            unsigned short* __restrict__ W2aT,
                            unsigned short* __restrict__ W2bT,
                            float* __restrict__ b2ap) {
    int idx = blockIdx.x * 256 + threadIdx.x;
    const int N1 = NPH * KP;            // 417792
    const int N2 = 32 * W2B_STRIDE;     // 25600
    if (idx < N1) {
        int c = idx / KP, k = idx - c * KP;
        float v = (c < H2 && k < QF) ? W2a[k * H2 + c] : 0.f;
        W2aT[idx] = f2bf(v);
    } else if (idx < N1 + N2) {
        int j = idx - N1;
        int c = j / W2B_STRIDE, k = j - c * W2B_STRIDE;
        float v = (k < H2) ? W2b[k * D + c] : 0.f;
        W2bT[j] = f2bf(v);
    } else if (idx < N1 + N2 + NPH) {
        int k = idx - N1 - N2;
        b2ap[k] = (k < H2) ? b2a[k] : 0.f;
    }
}

// ---------------- fused main kernel ----------------
// LDS (118 KB) limits to 1 block/CU = 8 waves = 2 waves/SIMD. Pin the
// compiler to exactly that occupancy: amdgpu_waves_per_eu(2,2) -> VGPR
// budget 256/wave. (__launch_bounds__'s 2nd arg is only a *min* waves/EU
// floor; the heuristic still picked 4 waves/EU -> 128 VGPRs -> 600 MB of
// scratch spill traffic, which was the entire 637 us.)
__global__ __launch_bounds__(512)
__attribute__((amdgpu_waves_per_eu(2, 2)))
void fused_kernel(
    const float* __restrict__ y,   const float* __restrict__ W1a,
    const float* __restrict__ b1a, const float* __restrict__ W1b,
    const float* __restrict__ b1b, const float* __restrict__ b2b,
    const unsigned short* __restrict__ W2aT, const unsigned short* __restrict__ W2bT,
    const float* __restrict__ b2ap, float* __restrict__ out) {

    __shared__ float          yls[64][36];     // y tile (stride 36: float4-aligned)
    __shared__ unsigned short quadls[64][552]; // bf16 quad, K padded to 544 (+8 bank pad)
    __shared__ float          h1ls[64][51];    // net1 hidden
    __shared__ float          outls[64][36];   // output accumulator
    __shared__ unsigned short hst[8][16][72];  // per-wave h re-stage tile

    const int tid  = threadIdx.x;
    const int lane = tid & 63;
    const int w    = tid >> 6;      // wave 0..7
    const int l15  = lane & 15;
    const int lg   = lane >> 4;     // 0..3
    const int row0 = blockIdx.x * 64;

    // ---- Phase A: load y tile, zero hst pad cols ----
    {
        int e = tid * 4;                 // 2048 floats total
        int r = e >> 5, c = e & 31;
        floatx4 v = *reinterpret_cast<const floatx4*>(y + (row0 + r) * D + c);
        *reinterpret_cast<floatx4*>(&yls[r][c]) = v;
    }
    for (int e = tid; e < 8 * 16 * 24; e += 512) {
        int ww = e / 384, rr = (e / 24) & 15, cc = 48 + (e % 24);
        hst[ww][rr][cc] = 0;
    }
    __syncthreads();

    // ---- Phase B: build quad (bf16) + net1 hidden ----
    #pragma unroll
    for (int s = 0; s < 4; ++s) {
        int task = tid + s * 512;        // (row, i) : 64*32 tasks
        int r = task >> 5, i = task & 31;
        int base = (i * (i + 1)) >> 1;
        float yi = yls[r][i];
        for (int j4 = 0; j4 <= i; j4 += 4) {
            floatx4 yv = *reinterpret_cast<const floatx4*>(&yls[r][j4]);
            #pragma unroll
            for (int jj = 0; jj < 4; ++jj) {
                int j = j4 + jj;
                if (j <= i) quadls[r][base + j] = f2bf(yi * yv[jj]);
            }
        }
    }
    for (int e = tid; e < 64 * 16; e += 512)   // zero K-pad 528..543
        quadls[e >> 4][528 + (e & 15)] = 0;

    if (tid < 208) {                     // net1 hidden: 16 row-groups x 13 col-groups
        int rowg = tid / 13, jg = tid - rowg * 13;
        int r0 = rowg * 4, c0 = jg * 4;
        int lim = (c0 + 4 <= H1) ? 4 : (H1 - c0);
        float acc[4][4];
        #pragma unroll
        for (int rr = 0; rr < 4; ++rr)
            #pragma unroll
            for (int jj = 0; jj < 4; ++jj)
                acc[rr][jj] = (jj < lim) ? b1a[c0 + jj] : 0.f;
        for (int i = 0; i < D; ++i) {
            float wv[4];
            #pragma unroll
            for (int jj = 0; jj < 4; ++jj)
                wv[jj] = (jj < lim) ? W1a[i * H1 + c0 + jj] : 0.f;
            #pragma unroll
            for (int rr = 0; rr < 4; ++rr) {
                float yv = yls[r0 + rr][i];
                #pragma unroll
                for (int jj = 0; jj < 4; ++jj) acc[rr][jj] += yv * wv[jj];
            }
        }
        #pragma unroll
        for (int rr = 0; rr < 4; ++rr)
            #pragma unroll
            for (int jj = 0; jj < 4; ++jj)
                if (jj < lim) h1ls[r0 + rr][c0 + jj] = tanh_fast(acc[rr][jj]);
    }
    __syncthreads();

    // ---- Phase C: out1 + all output biases into outls ----
    {
        int r = tid >> 3, c0 = (tid & 7) * 4;
        floatx4 acc;
        #pragma unroll
        for (int jj = 0; jj < 4; ++jj) acc[jj] = b1b[c0 + jj] + b2b[c0 + jj];
        for (int k = 0; k < H1; ++k) {
            float hv = h1ls[r][k];
            floatx4 wv = *reinterpret_cast<const floatx4*>(W1b + k * D + c0);
            #pragma unroll
            for (int jj = 0; jj < 4; ++jj) acc[jj] += hv * wv[jj];
        }
        *reinterpret_cast<floatx4*>(&outls[r][c0]) = acc;
    }
    __syncthreads();

    // ---- Main: wave w owns hidden cols [w*96, w*96+96), two halves of 48 ----
    floatx4 o2[4][2];
    #pragma unroll
    for (int m = 0; m < 4; ++m)
        #pragma unroll
        for (int of = 0; of < 2; ++of) o2[m][of] = (floatx4){0.f, 0.f, 0.f, 0.f};

    for (int half = 0; half < 2; ++half) {
        const int hb = w * 96 + half * 48;
        floatx4 hacc[4][3];
        #pragma unroll
        for (int m = 0; m < 4; ++m)
            #pragma unroll
            for (int nf = 0; nf < 3; ++nf) hacc[m][nf] = (floatx4){0.f, 0.f, 0.f, 0.f};

        const unsigned short* bpt = W2aT + (hb + l15) * KP + lg * 8;

        #pragma unroll
        for (int k = 0; k < 17; ++k) {
            short8x a[4];
            #pragma unroll
            for (int m = 0; m < 4; ++m)
                a[m] = *reinterpret_cast<const short8x*>(&quadls[m * 16 + l15][k * 32 + lg * 8]);
            short8x bfr[3];
            #pragma unroll
            for (int nf = 0; nf < 3; ++nf)
                bfr[nf] = *reinterpret_cast<const short8x*>(bpt + nf * 16 * KP + k * 32);
            #pragma unroll
            for (int m = 0; m < 4; ++m)
                #pragma unroll
                for (int nf = 0; nf < 3; ++nf)
                    hacc[m][nf] = __builtin_amdgcn_mfma_f32_16x16x32_bf16(a[m], bfr[nf], hacc[m][nf], 0, 0, 0);
        }

        // epilogue: bias + tanh -> bf16 re-stage -> second GEMM (K=64 incl zero pad)
        float bias[3];
        #pragma unroll
        for (int nf = 0; nf < 3; ++nf) bias[nf] = b2ap[hb + nf * 16 + l15];

        short8x bw[2][2];
        #pragma unroll
        for (int ks = 0; ks < 2; ++ks)
            #pragma unroll
            for (int of = 0; of < 2; ++of)
                bw[ks][of] = *reinterpret_cast<const short8x*>(
                    W2bT + (of * 16 + l15) * W2B_STRIDE + hb + ks * 32 + lg * 8);

        #pragma unroll
        for (int m = 0; m < 4; ++m) {
            #pragma unroll
            for (int nf = 0; nf < 3; ++nf)
                #pragma unroll
                for (int r = 0; r < 4; ++r)
                    hst[w][lg * 4 + r][nf * 16 + l15] =
                        f2bf(tanh_fast(hacc[m][nf][r] + bias[nf]));
            short8x aa0 = *reinterpret_cast<const short8x*>(&hst[w][l15][lg * 8]);
            short8x aa1 = *reinterpret_cast<const short8x*>(&hst[w][l15][32 + lg * 8]);
            o2[m][0] = __builtin_amdgcn_mfma_f32_16x16x32_bf16(aa0, bw[0][0], o2[m][0], 0, 0, 0);
            o2[m][1] = __builtin_amdgcn_mfma_f32_16x16x32_bf16(aa0, bw[0][1], o2[m][1], 0, 0, 0);
            o2[m][0] = __builtin_amdgcn_mfma_f32_16x16x32_bf16(aa1, bw[1][0], o2[m][0], 0, 0, 0);
            o2[m][1] = __builtin_amdgcn_mfma_f32_16x16x32_bf16(aa1, bw[1][1], o2[m][1], 0, 0, 0);
        }
    }

    // ---- deterministic cross-wave reduction into outls ----
    for (int ww = 0; ww < 8; ++ww) {
        if (w == ww) {
            #pragma unroll
            for (int m = 0; m < 4; ++m)
                #pragma unroll
                for (int of = 0; of < 2; ++of)
                    #pragma unroll
                    for (int r = 0; r < 4; ++r)
                        outls[m * 16 + lg * 4 + r][of * 16 + l15] += o2[m][of][r];
        }
        __syncthreads();
    }

    // ---- write out ----
    {
        int e = tid * 4;
        int r = e >> 5, c = e & 31;
        floatx4 v = *reinterpret_cast<const floatx4*>(&outls[r][c]);
        *reinterpret_cast<floatx4*>(out + (row0 + r) * D + c) = v;
    }
}

extern "C" void kernel_launch(void* const* d_in, const int* in_sizes, int n_in,
                              void* d_out, int out_size, void* d_ws, size_t ws_size,
                              hipStream_t stream) {
    const float* y   = (const float*)d_in[1];
    const float* W1a = (const float*)d_in[2];
    const float* b1a = (const float*)d_in[3];
    const float* W1b = (const float*)d_in[4];
    const float* b1b = (const float*)d_in[5];
    const float* W2a = (const float*)d_in[6];
    const float* b2a = (const float*)d_in[7];
    const float* W2b = (const float*)d_in[8];
    const float* b2b = (const float*)d_in[9];

    unsigned short* W2aT = (unsigned short*)d_ws;                          // 835584 B
    unsigned short* W2bT = (unsigned short*)((char*)d_ws + 835584);        //  51200 B
    float*          b2ap = (float*)((char*)d_ws + 835584 + 51200);         //   3072 B

    const int prep_tasks = NPH * KP + 32 * W2B_STRIDE + NPH;               // 444160
    prep_kernel<<<(prep_tasks + 255) / 256, 256, 0, stream>>>(W2a, b2a, W2b, W2aT, W2bT, b2ap);
    fused_kernel<<<B_TOT / 64, 512, 0, stream>>>(y, W1a, b1a, W1b, b1b, b2b,
                                                 W2aT, W2bT, b2ap, (float*)d_out);
}

// Round 4
// 324.113 us; speedup vs baseline: 1.9658x; 1.9428x over previous
//
#include <hip/hip_runtime.h>
#include <hip/hip_bf16.h>

#define B_TOT 131072
#define D     32
#define H1    50
#define QF    528     // tril feature count
#define H2    700
#define KP    544     // quad K padded to 17*32
#define NPH   768     // H2 padded to 8 waves * 96
#define W2B_STRIDE 800  // W2bT k-stride (>= 720+64, 16B-aligned)

typedef __attribute__((ext_vector_type(8))) short  short8x;
typedef __attribute__((ext_vector_type(4))) float  floatx4;

static __device__ __forceinline__ unsigned short f2bf(float f) {
    __hip_bfloat16 h = __float2bfloat16(f);   // RNE
    return __builtin_bit_cast(unsigned short, h);
}

static __device__ __forceinline__ float tanh_fast(float x) {
    float xc = fminf(15.f, fmaxf(-15.f, x));
    float e  = __expf(2.f * xc);
    return 1.f - 2.f * __builtin_amdgcn_rcpf(e + 1.f);
}

// ---------------- prep: convert/pad weights into workspace ----------------
__global__ void prep_kernel(const float* __restrict__ W2a, const float* __restrict__ b2a,
                            const float* __restrict__ W2b,
                            unsigned short* __restrict__ W2aT,
                            unsigned short* __restrict__ W2bT,
                            float* __restrict__ b2ap) {
    int idx = blockIdx.x * 256 + threadIdx.x;
    const int N1 = NPH * KP;            // 417792
    const int N2 = 32 * W2B_STRIDE;     // 25600
    if (idx < N1) {
        int c = idx / KP, k = idx - c * KP;
        float v = (c < H2 && k < QF) ? W2a[k * H2 + c] : 0.f;
        W2aT[idx] = f2bf(v);
    } else if (idx < N1 + N2) {
        int j = idx - N1;
        int c = j / W2B_STRIDE, k = j - c * W2B_STRIDE;
        float v = (k < H2) ? W2b[k * D + c] : 0.f;
        W2bT[j] = f2bf(v);
    } else if (idx < N1 + N2 + NPH) {
        int k = idx - N1 - N2;
        b2ap[k] = (k < H2) ? b2a[k] : 0.f;
    }
}

// ---------------- fused main kernel ----------------
// Spill-proof-by-construction version: per-half o2 accumulator flushed to
// LDS (keeps K-loop live set ~90 VGPRs), K-loop unroll capped at 4 so the
// scheduler can't hoist 51 global loads into flight. Attribute-based VGPR
// budget raises (launch_bounds min-waves, waves_per_eu) had zero effect on
// the allocator across rounds 1-3 (VGPR stuck at 128, 600 MB scratch).
__global__ __launch_bounds__(512)
__attribute__((amdgpu_waves_per_eu(2, 2)))
void fused_kernel(
    const float* __restrict__ y,   const float* __restrict__ W1a,
    const float* __restrict__ b1a, const float* __restrict__ W1b,
    const float* __restrict__ b1b, const float* __restrict__ b2b,
    const unsigned short* __restrict__ W2aT, const unsigned short* __restrict__ W2bT,
    const float* __restrict__ b2ap, float* __restrict__ out) {

    __shared__ float          yls[64][36];     // y tile
    __shared__ unsigned short quadls[64][552]; // bf16 quad, K padded to 544 (+8 bank pad)
    __shared__ float          h1ls[64][51];    // net1 hidden
    __shared__ float          outls[64][36];   // output accumulator
    __shared__ unsigned short hst[8][16][72];  // per-wave h re-stage tile

    const int tid  = threadIdx.x;
    const int lane = tid & 63;
    const int w    = tid >> 6;      // wave 0..7
    const int l15  = lane & 15;
    const int lg   = lane >> 4;     // 0..3
    const int row0 = blockIdx.x * 64;

    // ---- Phase A: load y tile, zero hst pad cols ----
    {
        int e = tid * 4;
        int r = e >> 5, c = e & 31;
        floatx4 v = *reinterpret_cast<const floatx4*>(y + (row0 + r) * D + c);
        *reinterpret_cast<floatx4*>(&yls[r][c]) = v;
    }
    for (int e = tid; e < 8 * 16 * 24; e += 512) {
        int ww = e / 384, rr = (e / 24) & 15, cc = 48 + (e % 24);
        hst[ww][rr][cc] = 0;
    }
    __syncthreads();

    // ---- Phase B: build quad (bf16) + net1 hidden ----
    #pragma unroll
    for (int s = 0; s < 4; ++s) {
        int task = tid + s * 512;
        int r = task >> 5, i = task & 31;
        int base = (i * (i + 1)) >> 1;
        float yi = yls[r][i];
        for (int j4 = 0; j4 <= i; j4 += 4) {
            floatx4 yv = *reinterpret_cast<const floatx4*>(&yls[r][j4]);
            #pragma unroll
            for (int jj = 0; jj < 4; ++jj) {
                int j = j4 + jj;
                if (j <= i) quadls[r][base + j] = f2bf(yi * yv[jj]);
            }
        }
    }
    for (int e = tid; e < 64 * 16; e += 512)
        quadls[e >> 4][528 + (e & 15)] = 0;

    if (tid < 208) {
        int rowg = tid / 13, jg = tid - rowg * 13;
        int r0 = rowg * 4, c0 = jg * 4;
        int lim = (c0 + 4 <= H1) ? 4 : (H1 - c0);
        float acc[4][4];
        #pragma unroll
        for (int rr = 0; rr < 4; ++rr)
            #pragma unroll
            for (int jj = 0; jj < 4; ++jj)
                acc[rr][jj] = (jj < lim) ? b1a[c0 + jj] : 0.f;
        for (int i = 0; i < D; ++i) {
            float wv[4];
            #pragma unroll
            for (int jj = 0; jj < 4; ++jj)
                wv[jj] = (jj < lim) ? W1a[i * H1 + c0 + jj] : 0.f;
            #pragma unroll
            for (int rr = 0; rr < 4; ++rr) {
                float yv = yls[r0 + rr][i];
                #pragma unroll
                for (int jj = 0; jj < 4; ++jj) acc[rr][jj] += yv * wv[jj];
            }
        }
        #pragma unroll
        for (int rr = 0; rr < 4; ++rr)
            #pragma unroll
            for (int jj = 0; jj < 4; ++jj)
                if (jj < lim) h1ls[r0 + rr][c0 + jj] = tanh_fast(acc[rr][jj]);
    }
    __syncthreads();

    // ---- Phase C: out1 + all output biases into outls ----
    {
        int r = tid >> 3, c0 = (tid & 7) * 4;
        floatx4 acc;
        #pragma unroll
        for (int jj = 0; jj < 4; ++jj) acc[jj] = b1b[c0 + jj] + b2b[c0 + jj];
        for (int k = 0; k < H1; ++k) {
            float hv = h1ls[r][k];
            floatx4 wv = *reinterpret_cast<const floatx4*>(W1b + k * D + c0);
            #pragma unroll
            for (int jj = 0; jj < 4; ++jj) acc[jj] += hv * wv[jj];
        }
        *reinterpret_cast<floatx4*>(&outls[r][c0]) = acc;
    }
    __syncthreads();

    // ---- Main: wave w owns hidden cols [w*96, w*96+96), two halves of 48 ----
    for (int half = 0; half < 2; ++half) {
        const int hb = w * 96 + half * 48;
        floatx4 hacc[4][3];
        #pragma unroll
        for (int m = 0; m < 4; ++m)
            #pragma unroll
            for (int nf = 0; nf < 3; ++nf) hacc[m][nf] = (floatx4){0.f, 0.f, 0.f, 0.f};

        const unsigned short* bpt = W2aT + (hb + l15) * KP + lg * 8;

        #pragma unroll 4
        for (int k = 0; k < 17; ++k) {
            short8x a[4];
            #pragma unroll
            for (int m = 0; m < 4; ++m)
                a[m] = *reinterpret_cast<const short8x*>(&quadls[m * 16 + l15][k * 32 + lg * 8]);
            short8x bfr[3];
            #pragma unroll
            for (int nf = 0; nf < 3; ++nf)
                bfr[nf] = *reinterpret_cast<const short8x*>(bpt + nf * 16 * KP + k * 32);
            #pragma unroll
            for (int m = 0; m < 4; ++m)
                #pragma unroll
                for (int nf = 0; nf < 3; ++nf)
                    hacc[m][nf] = __builtin_amdgcn_mfma_f32_16x16x32_bf16(a[m], bfr[nf], hacc[m][nf], 0, 0, 0);
        }

        // epilogue: bias + tanh -> bf16 re-stage -> second GEMM, o2h per-half
        float bias[3];
        #pragma unroll
        for (int nf = 0; nf < 3; ++nf) bias[nf] = b2ap[hb + nf * 16 + l15];

        short8x bw[2][2];
        #pragma unroll
        for (int ks = 0; ks < 2; ++ks)
            #pragma unroll
            for (int of = 0; of < 2; ++of)
                bw[ks][of] = *reinterpret_cast<const short8x*>(
                    W2bT + (of * 16 + l15) * W2B_STRIDE + hb + ks * 32 + lg * 8);

        floatx4 o2h[4][2];
        #pragma unroll
        for (int m = 0; m < 4; ++m)
            #pragma unroll
            for (int of = 0; of < 2; ++of) o2h[m][of] = (floatx4){0.f, 0.f, 0.f, 0.f};

        #pragma unroll
        for (int m = 0; m < 4; ++m) {
            #pragma unroll
            for (int nf = 0; nf < 3; ++nf)
                #pragma unroll
                for (int r = 0; r < 4; ++r)
                    hst[w][lg * 4 + r][nf * 16 + l15] =
                        f2bf(tanh_fast(hacc[m][nf][r] + bias[nf]));
            short8x aa0 = *reinterpret_cast<const short8x*>(&hst[w][l15][lg * 8]);
            short8x aa1 = *reinterpret_cast<const short8x*>(&hst[w][l15][32 + lg * 8]);
            o2h[m][0] = __builtin_amdgcn_mfma_f32_16x16x32_bf16(aa0, bw[0][0], o2h[m][0], 0, 0, 0);
            o2h[m][1] = __builtin_amdgcn_mfma_f32_16x16x32_bf16(aa0, bw[0][1], o2h[m][1], 0, 0, 0);
            o2h[m][0] = __builtin_amdgcn_mfma_f32_16x16x32_bf16(aa1, bw[1][0], o2h[m][0], 0, 0, 0);
            o2h[m][1] = __builtin_amdgcn_mfma_f32_16x16x32_bf16(aa1, bw[1][1], o2h[m][1], 0, 0, 0);
        }

        // deterministic cross-wave flush of this half's partial sums
        for (int ww = 0; ww < 8; ++ww) {
            if (w == ww) {
                #pragma unroll
                for (int m = 0; m < 4; ++m)
                    #pragma unroll
                    for (int of = 0; of < 2; ++of)
                        #pragma unroll
                        for (int r = 0; r < 4; ++r)
                            outls[m * 16 + lg * 4 + r][of * 16 + l15] += o2h[m][of][r];
            }
            __syncthreads();
        }
    }

    // ---- write out ----
    {
        int e = tid * 4;
        int r = e >> 5, c = e & 31;
        floatx4 v = *reinterpret_cast<const floatx4*>(&outls[r][c]);
        *reinterpret_cast<floatx4*>(out + (row0 + r) * D + c) = v;
    }
}

extern "C" void kernel_launch(void* const* d_in, const int* in_sizes, int n_in,
                              void* d_out, int out_size, void* d_ws, size_t ws_size,
                              hipStream_t stream) {
    const float* y   = (const float*)d_in[1];
    const float* W1a = (const float*)d_in[2];
    const float* b1a = (const float*)d_in[3];
    const float* W1b = (const float*)d_in[4];
    const float* b1b = (const float*)d_in[5];
    const float* W2a = (const float*)d_in[6];
    const float* b2a = (const float*)d_in[7];
    const float* W2b = (const float*)d_in[8];
    const float* b2b = (const float*)d_in[9];

    unsigned short* W2aT = (unsigned short*)d_ws;                          // 835584 B
    unsigned short* W2bT = (unsigned short*)((char*)d_ws + 835584);        //  51200 B
    float*          b2ap = (float*)((char*)d_ws + 835584 + 51200);         //   3072 B

    const int prep_tasks = NPH * KP + 32 * W2B_STRIDE + NPH;               // 444160
    prep_kernel<<<(prep_tasks + 255) / 256, 256, 0, stream>>>(W2a, b2a, W2b, W2aT, W2bT, b2ap);
    fused_kernel<<<B_TOT / 64, 512, 0, stream>>>(y, W1a, b1a, W1b, b1b, b2b,
                                                 W2aT, W2bT, b2ap, (float*)d_out);
}

// Round 5
// 291.345 us; speedup vs baseline: 2.1869x; 1.1125x over previous
//
#include <hip/hip_runtime.h>
#include <hip/hip_bf16.h>

#define B_TOT 131072
#define D     32
#define H1    50
#define QF    528     // tril feature count
#define H2    700
#define KP    544     // quad K padded to 17*32
#define NPH   768     // H2 padded to 16 waves * 48
#define W2B_STRIDE 800  // W2bT k-stride (>= 720+64, 16B-aligned)

typedef __attribute__((ext_vector_type(8))) short  short8x;
typedef __attribute__((ext_vector_type(4))) float  floatx4;

static __device__ __forceinline__ unsigned short f2bf(float f) {
    __hip_bfloat16 h = __float2bfloat16(f);   // RNE
    return __builtin_bit_cast(unsigned short, h);
}

static __device__ __forceinline__ float tanh_fast(float x) {
    float xc = fminf(15.f, fmaxf(-15.f, x));
    float e  = __expf(2.f * xc);
    return 1.f - 2.f * __builtin_amdgcn_rcpf(e + 1.f);
}

// ---------------- prep: convert/pad weights into workspace ----------------
__global__ void prep_kernel(const float* __restrict__ W2a, const float* __restrict__ b2a,
                            const float* __restrict__ W2b,
                            unsigned short* __restrict__ W2aT,
                            unsigned short* __restrict__ W2bT,
                            float* __restrict__ b2ap) {
    int idx = blockIdx.x * 256 + threadIdx.x;
    const int N1 = NPH * KP;            // 417792
    const int N2 = 32 * W2B_STRIDE;     // 25600
    if (idx < N1) {
        int c = idx / KP, k = idx - c * KP;
        float v = (c < H2 && k < QF) ? W2a[k * H2 + c] : 0.f;
        W2aT[idx] = f2bf(v);
    } else if (idx < N1 + N2) {
        int j = idx - N1;
        int c = j / W2B_STRIDE, k = j - c * W2B_STRIDE;
        float v = (k < H2) ? W2b[k * D + c] : 0.f;
        W2bT[j] = f2bf(v);
    } else if (idx < N1 + N2 + NPH) {
        int k = idx - N1 - N2;
        b2ap[k] = (k < H2) ? b2a[k] : 0.f;
    }
}

// ---------------- fused main kernel ----------------
// 16 waves (1024 thr), each owning 48 hidden cols in a single K-pass.
// Round-4 diagnosis: 2 waves/SIMD was latency-bound (all pipes <25%).
// Same total work, 2x issue density. LDS 139 KB -> still 1 block/CU.
__global__ __launch_bounds__(1024, 4)
__attribute__((amdgpu_waves_per_eu(4, 4)))
void fused_kernel(
    const float* __restrict__ y,   const float* __restrict__ W1a,
    const float* __restrict__ b1a, const float* __restrict__ W1b,
    const float* __restrict__ b1b, const float* __restrict__ b2b,
    const unsigned short* __restrict__ W2aT, const unsigned short* __restrict__ W2bT,
    const float* __restrict__ b2ap, float* __restrict__ out) {

    __shared__ float          yls[64][36];     // y tile
    __shared__ unsigned short quadls[64][552]; // bf16 quad, K padded to 544 (+8 pad)
    __shared__ float          h1ls[64][51];    // net1 hidden
    __shared__ float          outls[64][36];   // output accumulator
    __shared__ unsigned short hst[16][16][72]; // per-wave h re-stage tile

    const int tid  = threadIdx.x;
    const int lane = tid & 63;
    const int w    = tid >> 6;      // wave 0..15
    const int l15  = lane & 15;
    const int lg   = lane >> 4;     // 0..3
    const int row0 = blockIdx.x * 64;

    // ---- Phase A: load y tile, zero hst pad cols ----
    if (tid < 512) {
        int e = tid * 4;
        int r = e >> 5, c = e & 31;
        floatx4 v = *reinterpret_cast<const floatx4*>(y + (row0 + r) * D + c);
        *reinterpret_cast<floatx4*>(&yls[r][c]) = v;
    }
    for (int e = tid; e < 16 * 16 * 24; e += 1024) {
        int ww = e / 384, rr = (e / 24) & 15, cc = 48 + (e % 24);
        hst[ww][rr][cc] = 0;
    }
    __syncthreads();

    // ---- Phase B: build quad (bf16) + net1 hidden ----
    #pragma unroll
    for (int s = 0; s < 2; ++s) {
        int task = tid + s * 1024;       // (row, i) : 64*32 tasks
        int r = task >> 5, i = task & 31;
        int base = (i * (i + 1)) >> 1;
        float yi = yls[r][i];
        for (int j4 = 0; j4 <= i; j4 += 4) {
            floatx4 yv = *reinterpret_cast<const floatx4*>(&yls[r][j4]);
            #pragma unroll
            for (int jj = 0; jj < 4; ++jj) {
                int j = j4 + jj;
                if (j <= i) quadls[r][base + j] = f2bf(yi * yv[jj]);
            }
        }
    }
    {   // zero K-pad 528..543 (64*16 = 1024 elems)
        quadls[tid >> 4][528 + (tid & 15)] = 0;
    }

    if (tid < 208) {                     // net1 hidden
        int rowg = tid / 13, jg = tid - rowg * 13;
        int r0 = rowg * 4, c0 = jg * 4;
        int lim = (c0 + 4 <= H1) ? 4 : (H1 - c0);
        float acc[4][4];
        #pragma unroll
        for (int rr = 0; rr < 4; ++rr)
            #pragma unroll
            for (int jj = 0; jj < 4; ++jj)
                acc[rr][jj] = (jj < lim) ? b1a[c0 + jj] : 0.f;
        for (int i = 0; i < D; ++i) {
            float wv[4];
            #pragma unroll
            for (int jj = 0; jj < 4; ++jj)
                wv[jj] = (jj < lim) ? W1a[i * H1 + c0 + jj] : 0.f;
            #pragma unroll
            for (int rr = 0; rr < 4; ++rr) {
                float yv = yls[r0 + rr][i];
                #pragma unroll
                for (int jj = 0; jj < 4; ++jj) acc[rr][jj] += yv * wv[jj];
            }
        }
        #pragma unroll
        for (int rr = 0; rr < 4; ++rr)
            #pragma unroll
            for (int jj = 0; jj < 4; ++jj)
                if (jj < lim) h1ls[r0 + rr][c0 + jj] = tanh_fast(acc[rr][jj]);
    }
    __syncthreads();

    // ---- Phase C: out1 + all output biases into outls ----
    if (tid < 512) {
        int r = tid >> 3, c0 = (tid & 7) * 4;
        floatx4 acc;
        #pragma unroll
        for (int jj = 0; jj < 4; ++jj) acc[jj] = b1b[c0 + jj] + b2b[c0 + jj];
        for (int k = 0; k < H1; ++k) {
            float hv = h1ls[r][k];
            floatx4 wv = *reinterpret_cast<const floatx4*>(W1b + k * D + c0);
            #pragma unroll
            for (int jj = 0; jj < 4; ++jj) acc[jj] += hv * wv[jj];
        }
        *reinterpret_cast<floatx4*>(&outls[r][c0]) = acc;
    }
    __syncthreads();

    // ---- Main: wave w owns hidden cols [w*48, w*48+48), single pass ----
    const int hb = w * 48;
    floatx4 hacc[4][3];
    #pragma unroll
    for (int m = 0; m < 4; ++m)
        #pragma unroll
        for (int nf = 0; nf < 3; ++nf) hacc[m][nf] = (floatx4){0.f, 0.f, 0.f, 0.f};

    const unsigned short* bpt = W2aT + (hb + l15) * KP + lg * 8;

    #pragma unroll 4
    for (int k = 0; k < 17; ++k) {
        short8x a[4];
        #pragma unroll
        for (int m = 0; m < 4; ++m)
            a[m] = *reinterpret_cast<const short8x*>(&quadls[m * 16 + l15][k * 32 + lg * 8]);
        short8x bfr[3];
        #pragma unroll
        for (int nf = 0; nf < 3; ++nf)
            bfr[nf] = *reinterpret_cast<const short8x*>(bpt + nf * 16 * KP + k * 32);
        #pragma unroll
        for (int m = 0; m < 4; ++m)
            #pragma unroll
            for (int nf = 0; nf < 3; ++nf)
                hacc[m][nf] = __builtin_amdgcn_mfma_f32_16x16x32_bf16(a[m], bfr[nf], hacc[m][nf], 0, 0, 0);
    }

    // epilogue: bias + tanh -> bf16 re-stage -> second GEMM (K=64 incl zero pad)
    float bias[3];
    #pragma unroll
    for (int nf = 0; nf < 3; ++nf) bias[nf] = b2ap[hb + nf * 16 + l15];

    short8x bw[2][2];
    #pragma unroll
    for (int ks = 0; ks < 2; ++ks)
        #pragma unroll
        for (int of = 0; of < 2; ++of)
            bw[ks][of] = *reinterpret_cast<const short8x*>(
                W2bT + (of * 16 + l15) * W2B_STRIDE + hb + ks * 32 + lg * 8);

    floatx4 o2h[4][2];
    #pragma unroll
    for (int m = 0; m < 4; ++m)
        #pragma unroll
        for (int of = 0; of < 2; ++of) o2h[m][of] = (floatx4){0.f, 0.f, 0.f, 0.f};

    #pragma unroll
    for (int m = 0; m < 4; ++m) {
        #pragma unroll
        for (int nf = 0; nf < 3; ++nf)
            #pragma unroll
            for (int r = 0; r < 4; ++r)
                hst[w][lg * 4 + r][nf * 16 + l15] =
                    f2bf(tanh_fast(hacc[m][nf][r] + bias[nf]));
        short8x aa0 = *reinterpret_cast<const short8x*>(&hst[w][l15][lg * 8]);
        short8x aa1 = *reinterpret_cast<const short8x*>(&hst[w][l15][32 + lg * 8]);
        o2h[m][0] = __builtin_amdgcn_mfma_f32_16x16x32_bf16(aa0, bw[0][0], o2h[m][0], 0, 0, 0);
        o2h[m][1] = __builtin_amdgcn_mfma_f32_16x16x32_bf16(aa0, bw[0][1], o2h[m][1], 0, 0, 0);
        o2h[m][0] = __builtin_amdgcn_mfma_f32_16x16x32_bf16(aa1, bw[1][0], o2h[m][0], 0, 0, 0);
        o2h[m][1] = __builtin_amdgcn_mfma_f32_16x16x32_bf16(aa1, bw[1][1], o2h[m][1], 0, 0, 0);
    }

    // ---- deterministic cross-wave reduction into outls (16 serialized steps) ----
    for (int ww = 0; ww < 16; ++ww) {
        if (w == ww) {
            #pragma unroll
            for (int m = 0; m < 4; ++m)
                #pragma unroll
                for (int of = 0; of < 2; ++of)
                    #pragma unroll
                    for (int r = 0; r < 4; ++r)
                        outls[m * 16 + lg * 4 + r][of * 16 + l15] += o2h[m][of][r];
        }
        __syncthreads();
    }

    // ---- write out ----
    if (tid < 512) {
        int e = tid * 4;
        int r = e >> 5, c = e & 31;
        floatx4 v = *reinterpret_cast<const floatx4*>(&outls[r][c]);
        *reinterpret_cast<floatx4*>(out + (row0 + r) * D + c) = v;
    }
}

extern "C" void kernel_launch(void* const* d_in, const int* in_sizes, int n_in,
                              void* d_out, int out_size, void* d_ws, size_t ws_size,
                              hipStream_t stream) {
    const float* y   = (const float*)d_in[1];
    const float* W1a = (const float*)d_in[2];
    const float* b1a = (const float*)d_in[3];
    const float* W1b = (const float*)d_in[4];
    const float* b1b = (const float*)d_in[5];
    const float* W2a = (const float*)d_in[6];
    const float* b2a = (const float*)d_in[7];
    const float* W2b = (const float*)d_in[8];
    const float* b2b = (const float*)d_in[9];

    unsigned short* W2aT = (unsigned short*)d_ws;                          // 835584 B
    unsigned short* W2bT = (unsigned short*)((char*)d_ws + 835584);        //  51200 B
    float*          b2ap = (float*)((char*)d_ws + 835584 + 51200);         //   3072 B

    const int prep_tasks = NPH * KP + 32 * W2B_STRIDE + NPH;               // 444160
    prep_kernel<<<(prep_tasks + 255) / 256, 256, 0, stream>>>(W2a, b2a, W2b, W2aT, W2bT, b2ap);
    fused_kernel<<<B_TOT / 64, 1024, 0, stream>>>(y, W1a, b1a, W1b, b1b, b2b,
                                                  W2aT, W2bT, b2ap, (float*)d_out);
}

// Round 6
// 234.406 us; speedup vs baseline: 2.7180x; 1.2429x over previous
//
#include <hip/hip_runtime.h>
#include <hip/hip_bf16.h>

#define B_TOT 131072
#define D     32
#define H1    50
#define QF    528     // tril feature count
#define H2    700
#define KP    544     // quad K padded to 17*32
#define NPH   768     // H2 padded to 16 waves * 48
#define W2B_STRIDE 800  // W2bT k-stride (>= 720+64, 16B-aligned)

typedef __attribute__((ext_vector_type(8))) short  short8x;
typedef __attribute__((ext_vector_type(4))) float  floatx4;

static __device__ __forceinline__ unsigned short f2bf(float f) {
    __hip_bfloat16 h = __float2bfloat16(f);   // RNE
    return __builtin_bit_cast(unsigned short, h);
}

static __device__ __forceinline__ float tanh_fast(float x) {
    float xc = fminf(15.f, fmaxf(-15.f, x));
    float e  = __expf(2.f * xc);
    return 1.f - 2.f * __builtin_amdgcn_rcpf(e + 1.f);
}

// ---------------- prep: convert/pad weights into workspace ----------------
__global__ void prep_kernel(const float* __restrict__ W2a, const float* __restrict__ b2a,
                            const float* __restrict__ W2b,
                            unsigned short* __restrict__ W2aT,
                            unsigned short* __restrict__ W2bT,
                            float* __restrict__ b2ap) {
    int idx = blockIdx.x * 256 + threadIdx.x;
    const int N1 = NPH * KP;            // 417792
    const int N2 = 32 * W2B_STRIDE;     // 25600
    if (idx < N1) {
        int c = idx / KP, k = idx - c * KP;
        float v = (c < H2 && k < QF) ? W2a[k * H2 + c] : 0.f;
        W2aT[idx] = f2bf(v);
    } else if (idx < N1 + N2) {
        int j = idx - N1;
        int c = j / W2B_STRIDE, k = j - c * W2B_STRIDE;
        float v = (k < H2) ? W2b[k * D + c] : 0.f;
        W2bT[j] = f2bf(v);
    } else if (idx < N1 + N2 + NPH) {
        int k = idx - N1 - N2;
        b2ap[k] = (k < H2) ? b2a[k] : 0.f;
    }
}

// ---------------- fused main kernel ----------------
// Round-6 restructure: kill serialized phases. net1 is distributed per-wave
// AFTER the K-loop (off the barrier-critical path); the 16-step serialized
// cross-wave flush becomes a 2-group parallel staged reduce reusing quadls
// (dead after the K-loop) as f32 staging. Barriers ~22 -> ~8.
__global__ __launch_bounds__(1024, 4)
__attribute__((amdgpu_waves_per_eu(4, 4)))
void fused_kernel(
    const float* __restrict__ y,   const float* __restrict__ W1a,
    const float* __restrict__ b1a, const float* __restrict__ W1b,
    const float* __restrict__ b1b, const float* __restrict__ b2b,
    const unsigned short* __restrict__ W2aT, const unsigned short* __restrict__ W2bT,
    const float* __restrict__ b2ap, float* __restrict__ out) {

    __shared__ unsigned short quadls[64][552]; // 70656 B; reused post-K as f32 staging (65536 B)
    __shared__ float          yls[64][36];     //  9216 B
    __shared__ float          outls[64][36];   //  9216 B
    __shared__ unsigned short hst[16][16][72]; // 36864 B per-wave h re-stage
    __shared__ float          h1w[16][4][52];  // 13312 B per-wave net1 hidden

    const int tid  = threadIdx.x;
    const int lane = tid & 63;
    const int w    = tid >> 6;      // wave 0..15
    const int l15  = lane & 15;
    const int lg   = lane >> 4;     // 0..3
    const int row0 = blockIdx.x * 64;

    // ---- Phase A: load y tile, zero hst K-pad cols ----
    if (tid < 512) {
        int e = tid * 4;
        int r = e >> 5, c = e & 31;
        floatx4 v = *reinterpret_cast<const floatx4*>(y + (row0 + r) * D + c);
        *reinterpret_cast<floatx4*>(&yls[r][c]) = v;
    }
    for (int e = tid; e < 16 * 16 * 24; e += 1024) {
        int ww = e / 384, rr = (e / 24) & 15, cc = 48 + (e % 24);
        hst[ww][rr][cc] = 0;
    }
    __syncthreads();

    // ---- Phase B: build quad (bf16), zero K-pad ----
    #pragma unroll
    for (int s = 0; s < 2; ++s) {
        int task = tid + s * 1024;       // (row, i) : 64*32 tasks
        int r = task >> 5, i = task & 31;
        int base = (i * (i + 1)) >> 1;
        float yi = yls[r][i];
        for (int j4 = 0; j4 <= i; j4 += 4) {
            floatx4 yv = *reinterpret_cast<const floatx4*>(&yls[r][j4]);
            #pragma unroll
            for (int jj = 0; jj < 4; ++jj) {
                int j = j4 + jj;
                if (j <= i) quadls[r][base + j] = f2bf(yi * yv[jj]);
            }
        }
    }
    quadls[tid >> 4][528 + (tid & 15)] = 0;   // K-pad 528..543
    __syncthreads();

    // ---- Main: wave w owns hidden cols [w*48, w*48+48), single K-pass ----
    const int hb = w * 48;
    floatx4 hacc[4][3];
    #pragma unroll
    for (int m = 0; m < 4; ++m)
        #pragma unroll
        for (int nf = 0; nf < 3; ++nf) hacc[m][nf] = (floatx4){0.f, 0.f, 0.f, 0.f};

    const unsigned short* bpt = W2aT + (hb + l15) * KP + lg * 8;

    #pragma unroll 4
    for (int k = 0; k < 17; ++k) {
        short8x a[4];
        #pragma unroll
        for (int m = 0; m < 4; ++m)
            a[m] = *reinterpret_cast<const short8x*>(&quadls[m * 16 + l15][k * 32 + lg * 8]);
        short8x bfr[3];
        #pragma unroll
        for (int nf = 0; nf < 3; ++nf)
            bfr[nf] = *reinterpret_cast<const short8x*>(bpt + nf * 16 * KP + k * 32);
        #pragma unroll
        for (int m = 0; m < 4; ++m)
            #pragma unroll
            for (int nf = 0; nf < 3; ++nf)
                hacc[m][nf] = __builtin_amdgcn_mfma_f32_16x16x32_bf16(a[m], bfr[nf], hacc[m][nf], 0, 0, 0);
    }

    // ---- epilogue: bias + tanh -> bf16 re-stage -> second GEMM (K=64) ----
    float bias[3];
    #pragma unroll
    for (int nf = 0; nf < 3; ++nf) bias[nf] = b2ap[hb + nf * 16 + l15];

    short8x bw[2][2];
    #pragma unroll
    for (int ks = 0; ks < 2; ++ks)
        #pragma unroll
        for (int of = 0; of < 2; ++of)
            bw[ks][of] = *reinterpret_cast<const short8x*>(
                W2bT + (of * 16 + l15) * W2B_STRIDE + hb + ks * 32 + lg * 8);

    floatx4 o2h[4][2];
    #pragma unroll
    for (int m = 0; m < 4; ++m)
        #pragma unroll
        for (int of = 0; of < 2; ++of) o2h[m][of] = (floatx4){0.f, 0.f, 0.f, 0.f};

    #pragma unroll
    for (int m = 0; m < 4; ++m) {
        #pragma unroll
        for (int nf = 0; nf < 3; ++nf)
            #pragma unroll
            for (int r = 0; r < 4; ++r)
                hst[w][lg * 4 + r][nf * 16 + l15] =
                    f2bf(tanh_fast(hacc[m][nf][r] + bias[nf]));
        short8x aa0 = *reinterpret_cast<const short8x*>(&hst[w][l15][lg * 8]);
        short8x aa1 = *reinterpret_cast<const short8x*>(&hst[w][l15][32 + lg * 8]);
        o2h[m][0] = __builtin_amdgcn_mfma_f32_16x16x32_bf16(aa0, bw[0][0], o2h[m][0], 0, 0, 0);
        o2h[m][1] = __builtin_amdgcn_mfma_f32_16x16x32_bf16(aa0, bw[0][1], o2h[m][1], 0, 0, 0);
        o2h[m][0] = __builtin_amdgcn_mfma_f32_16x16x32_bf16(aa1, bw[1][0], o2h[m][0], 0, 0, 0);
        o2h[m][1] = __builtin_amdgcn_mfma_f32_16x16x32_bf16(aa1, bw[1][1], o2h[m][1], 0, 0, 0);
    }

    // ---- net1, distributed: wave w computes out1 for its 4 rows ----
    {
        // h1: lane (r1 = lane&3, cols c1 + 16t)
        int r1 = lane & 3;
        int c1 = lane >> 2;               // 0..15
        int rowa = w * 4 + r1;
        #pragma unroll
        for (int t = 0; t < 4; ++t) {
            int col = c1 + 16 * t;
            if (col < H1) {
                float acc = b1a[col];
                #pragma unroll 8
                for (int i = 0; i < D; ++i)
                    acc += yls[rowa][i] * W1a[i * H1 + col];
                h1w[w][r1][col] = tanh_fast(acc);
            }
        }
        // out1: lane (r2 = lane>>4, cols c2 and c2+16), init outls with all biases
        int r2 = lane >> 4;
        int c2 = lane & 15;
        float acc0 = b1b[c2]      + b2b[c2];
        float acc1 = b1b[c2 + 16] + b2b[c2 + 16];
        #pragma unroll 5
        for (int k = 0; k < H1; ++k) {
            float hv = h1w[w][r2][k];
            acc0 += hv * W1b[k * D + c2];
            acc1 += hv * W1b[k * D + c2 + 16];
        }
        outls[w * 4 + r2][c2]      = acc0;
        outls[w * 4 + r2][c2 + 16] = acc1;
    }
    __syncthreads();   // K-loop reads of quadls done everywhere; outls initialized

    // ---- parallel staged reduce of o2h into outls (2 groups of 8) ----
    float* stagef = (float*)&quadls[0][0];   // 8 panels * 2048 f32 = 64 KB
    const int rrow = w * 4 + (lane >> 4);    // this wave's outls row for reduce
    const int rcol = (lane & 15) * 2;

    // G1: waves 8..15 stage
    if (w >= 8) {
        int p = w - 8;
        #pragma unroll
        for (int m = 0; m < 4; ++m)
            #pragma unroll
            for (int of = 0; of < 2; ++of)
                #pragma unroll
                for (int r = 0; r < 4; ++r)
                    stagef[p * 2048 + (m * 16 + lg * 4 + r) * 32 + of * 16 + l15] = o2h[m][of][r];
    }
    __syncthreads();
    {
        float s0 = 0.f, s1 = 0.f;
        #pragma unroll
        for (int p = 0; p < 8; ++p) {
            s0 += stagef[p * 2048 + rrow * 32 + rcol];
            s1 += stagef[p * 2048 + rrow * 32 + rcol + 1];
        }
        outls[rrow][rcol]     += s0;
        outls[rrow][rcol + 1] += s1;
    }
    __syncthreads();
    // G2: waves 0..7 stage
    if (w < 8) {
        #pragma unroll
        for (int m = 0; m < 4; ++m)
            #pragma unroll
            for (int of = 0; of < 2; ++of)
                #pragma unroll
                for (int r = 0; r < 4; ++r)
                    stagef[w * 2048 + (m * 16 + lg * 4 + r) * 32 + of * 16 + l15] = o2h[m][of][r];
    }
    __syncthreads();
    {
        float s0 = 0.f, s1 = 0.f;
        #pragma unroll
        for (int p = 0; p < 8; ++p) {
            s0 += stagef[p * 2048 + rrow * 32 + rcol];
            s1 += stagef[p * 2048 + rrow * 32 + rcol + 1];
        }
        outls[rrow][rcol]     += s0;
        outls[rrow][rcol + 1] += s1;
    }
    __syncthreads();

    // ---- write out ----
    if (tid < 512) {
        int e = tid * 4;
        int r = e >> 5, c = e & 31;
        floatx4 v = *reinterpret_cast<const floatx4*>(&outls[r][c]);
        *reinterpret_cast<floatx4*>(out + (row0 + r) * D + c) = v;
    }
}

extern "C" void kernel_launch(void* const* d_in, const int* in_sizes, int n_in,
                              void* d_out, int out_size, void* d_ws, size_t ws_size,
                              hipStream_t stream) {
    const float* y   = (const float*)d_in[1];
    const float* W1a = (const float*)d_in[2];
    const float* b1a = (const float*)d_in[3];
    const float* W1b = (const float*)d_in[4];
    const float* b1b = (const float*)d_in[5];
    const float* W2a = (const float*)d_in[6];
    const float* b2a = (const float*)d_in[7];
    const float* W2b = (const float*)d_in[8];
    const float* b2b = (const float*)d_in[9];

    unsigned short* W2aT = (unsigned short*)d_ws;                          // 835584 B
    unsigned short* W2bT = (unsigned short*)((char*)d_ws + 835584);        //  51200 B
    float*          b2ap = (float*)((char*)d_ws + 835584 + 51200);         //   3072 B

    const int prep_tasks = NPH * KP + 32 * W2B_STRIDE + NPH;               // 444160
    prep_kernel<<<(prep_tasks + 255) / 256, 256, 0, stream>>>(W2a, b2a, W2b, W2aT, W2bT, b2ap);
    fused_kernel<<<B_TOT / 64, 1024, 0, stream>>>(y, W1a, b1a, W1b, b1b, b2b,
                                                  W2aT, W2bT, b2ap, (float*)d_out);
}